// Round 1
// baseline (352.879 us; speedup 1.0000x reference)
//
#include <hip/hip_runtime.h>

// Problem constants
#define B_    2
#define S_    2048
#define DIN   1024
#define DOUT  1024
#define H_    16
#define HD_   64
#define M_    (B_ * S_)   // 4096 rows total

typedef __bf16 bf16x8 __attribute__((ext_vector_type(8)));
typedef float  f32x4  __attribute__((ext_vector_type(4)));

__device__ __forceinline__ f32x4 MFMA(bf16x8 a, bf16x8 b, f32x4 c) {
    return __builtin_amdgcn_mfma_f32_16x16x32_bf16(a, b, c, 0, 0, 0);
}

// float -> bf16 bits, round-to-nearest-even
__device__ __forceinline__ unsigned short f2b(float f) {
    union { float f; unsigned int u; } v; v.f = f;
    unsigned int u = v.u;
    return (unsigned short)((u + 0x7fffu + ((u >> 16) & 1u)) >> 16);
}

// ---------------- convert x (f32 -> bf16), vectorized ----------------
__global__ void k_cvt_x(const float* __restrict__ x, unsigned short* __restrict__ xb) {
    int i = (blockIdx.x * blockDim.x + threadIdx.x) * 4;
    float4 v = *reinterpret_cast<const float4*>(x + i);
    ushort4 o;
    o.x = f2b(v.x); o.y = f2b(v.y); o.z = f2b(v.z); o.w = f2b(v.w);
    *reinterpret_cast<ushort4*>(xb + i) = o;
}

// ------------- convert + transpose weight (f32 KxN -> bf16 NxK) -------------
// block (32,8), grid (N/32, K/32); here K == N == 1024
__global__ void k_cvt_wT(const float* __restrict__ w, unsigned short* __restrict__ wt) {
    __shared__ float tile[32][33];
    int n0 = blockIdx.x * 32, k0 = blockIdx.y * 32;
    int tx = threadIdx.x, ty = threadIdx.y;
    for (int i = 0; i < 4; i++)
        tile[ty + i * 8][tx] = w[(size_t)(k0 + ty + i * 8) * DOUT + n0 + tx];
    __syncthreads();
    for (int i = 0; i < 4; i++)
        wt[(size_t)(n0 + ty + i * 8) * DIN + k0 + tx] = f2b(tile[tx][ty + i * 8]);
}

// ---------------- bf16 MFMA GEMM: C[M,N] = A[M,K] @ Bt[N,K]^T ----------------
// OUT_MODE 0: bf16 row-major out
// OUT_MODE 1: bf16 out stored transposed per (b,h): [(b*H+h)*HD + hd][S] (for V)
// OUT_MODE 2: f32 out + bias
// 128x128 tile, 4 waves (2x2), each wave 64x64 = 4x4 frags of 16x16, BK=32.
template <int OUT_MODE>
__global__ __launch_bounds__(256) void k_gemm(const unsigned short* __restrict__ A,
                                              const unsigned short* __restrict__ Bt,
                                              void* __restrict__ Cv,
                                              const float* __restrict__ bias,
                                              int M, int N, int K) {
    __shared__ unsigned short As[128 * 32];
    __shared__ unsigned short Bs[128 * 32];
    int m0 = blockIdx.y * 128, n0 = blockIdx.x * 128;
    int tid = threadIdx.x;
    int wid = tid >> 6, lane = tid & 63;
    int wm = wid >> 1, wn = wid & 1;
    int lr = lane & 15, lg = lane >> 4;

    f32x4 acc[4][4] = {};

    int sr = tid >> 2;            // 0..63
    int sc = (tid & 3) << 3;      // 0,8,16,24

    for (int k0 = 0; k0 < K; k0 += 32) {
        // stage A tile 128x32 and Bt tile 128x32 (16B per thread per half)
        {
            const unsigned short* Ag = A + (size_t)(m0 + sr) * K + k0 + sc;
            *reinterpret_cast<int4*>(&As[sr * 32 + sc]) = *reinterpret_cast<const int4*>(Ag);
            *reinterpret_cast<int4*>(&As[(sr + 64) * 32 + sc]) =
                *reinterpret_cast<const int4*>(Ag + (size_t)64 * K);
            const unsigned short* Bg = Bt + (size_t)(n0 + sr) * K + k0 + sc;
            *reinterpret_cast<int4*>(&Bs[sr * 32 + sc]) = *reinterpret_cast<const int4*>(Bg);
            *reinterpret_cast<int4*>(&Bs[(sr + 64) * 32 + sc]) =
                *reinterpret_cast<const int4*>(Bg + (size_t)64 * K);
        }
        __syncthreads();

        bf16x8 af[4], bf[4];
        for (int mi = 0; mi < 4; mi++)
            af[mi] = *reinterpret_cast<const bf16x8*>(&As[(wm * 64 + mi * 16 + lr) * 32 + lg * 8]);
        for (int ni = 0; ni < 4; ni++)
            bf[ni] = *reinterpret_cast<const bf16x8*>(&Bs[(wn * 64 + ni * 16 + lr) * 32 + lg * 8]);
        for (int mi = 0; mi < 4; mi++)
            for (int ni = 0; ni < 4; ni++)
                acc[mi][ni] = MFMA(af[mi], bf[ni], acc[mi][ni]);
        __syncthreads();
    }

    for (int mi = 0; mi < 4; mi++)
        for (int ni = 0; ni < 4; ni++)
            for (int i = 0; i < 4; i++) {
                int row = m0 + wm * 64 + mi * 16 + lg * 4 + i;
                int col = n0 + wn * 64 + ni * 16 + lr;
                float v = acc[mi][ni][i];
                if (OUT_MODE == 2) {
                    ((float*)Cv)[(size_t)row * N + col] = v + bias[col];
                } else if (OUT_MODE == 0) {
                    ((unsigned short*)Cv)[(size_t)row * N + col] = f2b(v);
                } else {
                    int bb = row >> 11, ss = row & (S_ - 1);
                    int hh = col >> 6, hd = col & (HD_ - 1);
                    ((unsigned short*)Cv)[((size_t)(bb * H_ + hh) * HD_ + hd) * S_ + ss] = f2b(v);
                }
            }
}

// ---------------- flash attention (causal), bf16 in/out ----------------
// grid (S/64, B*H), 256 threads. Wave w handles 16 q-rows. KV tiles of 64.
// Q,K layout: [b*S + s][h*HD + d] (stride DOUT). V layout: [(b*H+h)*HD + d][s].
__global__ __launch_bounds__(256) void k_attn(const unsigned short* __restrict__ Q,
                                              const unsigned short* __restrict__ Kg,
                                              const unsigned short* __restrict__ Vt,
                                              unsigned short* __restrict__ ctx) {
    int qt = blockIdx.x, bh = blockIdx.y;
    int b = bh >> 4, h = bh & 15;
    int tid = threadIdx.x, wid = tid >> 6, lane = tid & 63;
    int lr = lane & 15, lg = lane >> 4;
    int q0 = qt * 64 + wid * 16;

    __shared__ unsigned short p_lds[4][16 * 64];
    unsigned short* pl = p_lds[wid];

    const unsigned short* Qp = Q  + (size_t)b * S_ * DOUT + (size_t)h * HD_;
    const unsigned short* Kp = Kg + (size_t)b * S_ * DOUT + (size_t)h * HD_;
    const unsigned short* Vp = Vt + (size_t)(b * H_ + h) * HD_ * S_;

    bf16x8 qf[2];
    for (int kk = 0; kk < 2; kk++)
        qf[kk] = *reinterpret_cast<const bf16x8*>(&Qp[(size_t)(q0 + lr) * DOUT + kk * 32 + lg * 8]);

    f32x4 o[4] = {};
    float m_run[4], l_run[4];
    for (int i = 0; i < 4; i++) { m_run[i] = -1e30f; l_run[i] = 0.f; }

    int ntile = (q0 + 15) / 64 + 1;
    for (int t = 0; t < ntile; t++) {
        int kv0 = t * 64;
        // scores = Q @ K^T  (C layout: row q = lg*4+i, col kv = nf*16+lr)
        f32x4 sco[4];
        for (int nf = 0; nf < 4; nf++) {
            f32x4 z = {};
            for (int kk = 0; kk < 2; kk++) {
                bf16x8 kf = *reinterpret_cast<const bf16x8*>(
                    &Kp[(size_t)(kv0 + nf * 16 + lr) * DOUT + kk * 32 + lg * 8]);
                z = MFMA(qf[kk], kf, z);
            }
            sco[nf] = z;
        }
        // online softmax per q-row
        for (int i = 0; i < 4; i++) {
            int q = q0 + lg * 4 + i;
            float rm = -1e30f;
            for (int nf = 0; nf < 4; nf++) {
                float s = sco[nf][i] * 0.125f;      // 1/sqrt(64)
                if (kv0 + nf * 16 + lr > q) s = -1e30f;
                sco[nf][i] = s;
                rm = fmaxf(rm, s);
            }
            rm = fmaxf(rm, __shfl_xor(rm, 1, 64));
            rm = fmaxf(rm, __shfl_xor(rm, 2, 64));
            rm = fmaxf(rm, __shfl_xor(rm, 4, 64));
            rm = fmaxf(rm, __shfl_xor(rm, 8, 64));
            float mnew = fmaxf(m_run[i], rm);
            float sum = 0.f;
            for (int nf = 0; nf < 4; nf++) {
                float p = __expf(sco[nf][i] - mnew);
                sum += p;
                pl[(lg * 4 + i) * 64 + nf * 16 + lr] = f2b(p);
            }
            sum += __shfl_xor(sum, 1, 64);
            sum += __shfl_xor(sum, 2, 64);
            sum += __shfl_xor(sum, 4, 64);
            sum += __shfl_xor(sum, 8, 64);
            float cf = __expf(m_run[i] - mnew);
            l_run[i] = l_run[i] * cf + sum;
            m_run[i] = mnew;
            for (int nd = 0; nd < 4; nd++) o[nd][i] *= cf;
        }
        // P (A-frag via LDS) @ V
        bf16x8 pf[2];
        for (int kk = 0; kk < 2; kk++)
            pf[kk] = *reinterpret_cast<const bf16x8*>(&pl[lr * 64 + kk * 32 + lg * 8]);
        for (int nd = 0; nd < 4; nd++)
            for (int kk = 0; kk < 2; kk++) {
                bf16x8 vf = *reinterpret_cast<const bf16x8*>(
                    &Vp[(size_t)(nd * 16 + lr) * S_ + kv0 + kk * 32 + lg * 8]);
                o[nd] = MFMA(pf[kk], vf, o[nd]);
            }
    }
    // normalize + store ctx (bf16, [b*S+s][h*HD+d])
    for (int nd = 0; nd < 4; nd++)
        for (int i = 0; i < 4; i++) {
            float v = o[nd][i] / l_run[i];
            ctx[((size_t)b * S_ + q0 + lg * 4 + i) * DOUT + h * HD_ + nd * 16 + lr] = f2b(v);
        }
}

extern "C" void kernel_launch(void* const* d_in, const int* in_sizes, int n_in,
                              void* d_out, int out_size, void* d_ws, size_t ws_size,
                              hipStream_t stream) {
    const float* x  = (const float*)d_in[0];
    const float* Wq = (const float*)d_in[1];
    const float* Wk = (const float*)d_in[2];
    const float* Wv = (const float*)d_in[3];
    const float* Wo = (const float*)d_in[4];
    const float* bo = (const float*)d_in[5];
    float* out = (float*)d_out;
    char* ws = (char*)d_ws;
    const size_t MB = 1u << 20;

    // workspace layout (40 MB total; ctx reuses xb after projections)
    unsigned short* xb  = (unsigned short*)(ws);            // 8 MB (M_*DIN bf16)
    unsigned short* WqT = (unsigned short*)(ws + 8 * MB);   // 2 MB
    unsigned short* WkT = (unsigned short*)(ws + 10 * MB);  // 2 MB
    unsigned short* WvT = (unsigned short*)(ws + 12 * MB);  // 2 MB
    unsigned short* WoT = (unsigned short*)(ws + 14 * MB);  // 2 MB
    unsigned short* Qb  = (unsigned short*)(ws + 16 * MB);  // 8 MB
    unsigned short* Kb  = (unsigned short*)(ws + 24 * MB);  // 8 MB
    unsigned short* Vtb = (unsigned short*)(ws + 32 * MB);  // 8 MB
    unsigned short* ctx = xb;                               // reuse (x no longer needed)

    (void)in_sizes; (void)n_in; (void)out_size; (void)ws_size;

    // x -> bf16
    k_cvt_x<<<dim3((M_ * DIN) / 1024), 256, 0, stream>>>(x, xb);

    // weights -> bf16, transposed to NxK
    dim3 tb(32, 8), tg(DOUT / 32, DIN / 32);
    k_cvt_wT<<<tg, tb, 0, stream>>>(Wq, WqT);
    k_cvt_wT<<<tg, tb, 0, stream>>>(Wk, WkT);
    k_cvt_wT<<<tg, tb, 0, stream>>>(Wv, WvT);
    k_cvt_wT<<<tg, tb, 0, stream>>>(Wo, WoT);

    // QKV projections
    dim3 gg(DOUT / 128, M_ / 128);
    k_gemm<0><<<gg, 256, 0, stream>>>(xb, WqT, Qb,  nullptr, M_, DOUT, DIN);
    k_gemm<0><<<gg, 256, 0, stream>>>(xb, WkT, Kb,  nullptr, M_, DOUT, DIN);
    k_gemm<1><<<gg, 256, 0, stream>>>(xb, WvT, Vtb, nullptr, M_, DOUT, DIN);

    // causal flash attention
    dim3 ga(S_ / 64, B_ * H_);
    k_attn<<<ga, 256, 0, stream>>>(Qb, Kb, Vtb, ctx);

    // output projection + bias (f32 out)
    k_gemm<2><<<gg, 256, 0, stream>>>(ctx, WoT, (void*)out, bo, M_, DOUT, DOUT);
}